// Round 1
// baseline (5893.221 us; speedup 1.0000x reference)
//
#include <hip/hip_runtime.h>
#include <math.h>

#define HW 9216
#define IMG 96

// ---------------------------------------------------------------------------
// 1x1 conv (GEMM): xd[n,co,p] = b[co] + sum_ci w[co,ci] * x[n,ci,p]
// tile: 64co x 64p, K-chunk 16, block 256 (16x16), 4x4 micro-tile/thread
// ---------------------------------------------------------------------------
__global__ __launch_bounds__(256) void conv1x1_kernel(
    const float* __restrict__ in, const float* __restrict__ wgt,
    const float* __restrict__ bias, float* __restrict__ out)
{
    __shared__ float a_s[16][68];   // [k][co], pad 68: 16B-aligned rows, conflict-free
    __shared__ float b_s[16][64];   // [k][p]
    const int pb  = blockIdx.x * 64;
    const int co0 = blockIdx.y * 64;
    const int n   = blockIdx.z;
    const int tid = threadIdx.x;
    const int tx = tid & 15, ty = tid >> 4;
    float acc[4][4];
    #pragma unroll
    for (int i = 0; i < 4; ++i)
        #pragma unroll
        for (int j = 0; j < 4; ++j) acc[i][j] = 0.f;

    for (int k0 = 0; k0 < 512; k0 += 16) {
        #pragma unroll
        for (int t = 0; t < 4; ++t) {
            int idx = tid + t * 256;
            int c = idx >> 4, k = idx & 15;
            a_s[k][c] = wgt[(co0 + c) * 512 + k0 + k];
        }
        #pragma unroll
        for (int t = 0; t < 4; ++t) {
            int idx = tid + t * 256;
            int k = idx >> 6, p = idx & 63;
            b_s[k][p] = in[((long)n * 512 + k0 + k) * HW + pb + p];
        }
        __syncthreads();
        #pragma unroll
        for (int kk = 0; kk < 16; ++kk) {
            float4 av4 = *reinterpret_cast<const float4*>(&a_s[kk][ty * 4]);
            float4 bv4 = *reinterpret_cast<const float4*>(&b_s[kk][tx * 4]);
            float a[4] = {av4.x, av4.y, av4.z, av4.w};
            float b[4] = {bv4.x, bv4.y, bv4.z, bv4.w};
            #pragma unroll
            for (int i = 0; i < 4; ++i)
                #pragma unroll
                for (int j = 0; j < 4; ++j)
                    acc[i][j] += a[i] * b[j];
        }
        __syncthreads();
    }
    #pragma unroll
    for (int i = 0; i < 4; ++i) {
        int co = co0 + ty * 4 + i;
        float bb = bias[co];
        #pragma unroll
        for (int j = 0; j < 4; ++j)
            out[((long)n * 256 + co) * HW + pb + tx * 4 + j] = acc[i][j] + bb;
    }
}

// ---------------------------------------------------------------------------
// Generic direct 3x3 conv, pad=1. Input optionally split across two buffers
// (ci < cin1 -> in1 else in2). Block: 16 co x (8 rows x 96 cols), ci-chunk 8.
// Optional epilogue: bias; or bn*g+b then PReLU (for the final fuse conv).
// ---------------------------------------------------------------------------
__global__ __launch_bounds__(256) void conv3x3_kernel(
    const float* __restrict__ in1, int cin1, long ns1,
    const float* __restrict__ in2, int cin2, long ns2,
    const float* __restrict__ wgt, const float* __restrict__ bias,
    float* __restrict__ out, long nso,
    const float* __restrict__ bng, const float* __restrict__ bnb,
    const float* __restrict__ pra)
{
    const int h0  = blockIdx.x * 8;
    const int co0 = blockIdx.y * 16;
    const int n   = blockIdx.z;
    const int tid = threadIdx.x;
    const int cin = cin1 + cin2;

    __shared__ float in_s[8][10][98];
    __shared__ float w_s[8][9][16];   // [ci][tap][co] -> float4-able broadcast reads

    float acc[16][3];
    #pragma unroll
    for (int co = 0; co < 16; ++co)
        #pragma unroll
        for (int j = 0; j < 3; ++j) acc[co][j] = 0.f;

    int r_[3], c_[3];
    #pragma unroll
    for (int j = 0; j < 3; ++j) { int px = tid + j * 256; r_[j] = px / 96; c_[j] = px % 96; }

    for (int ci0 = 0; ci0 < cin; ci0 += 8) {
        for (int idx = tid; idx < 7840; idx += 256) {       // 8*10*98
            int ci = idx / 980, rem = idx % 980;
            int r = rem / 98, c = rem % 98;
            int gh = h0 + r - 1, gw = c - 1;
            float v = 0.f;
            if (gh >= 0 && gh < 96 && gw >= 0 && gw < 96) {
                int cg = ci0 + ci;
                v = (cg < cin1)
                  ? in1[(long)n * ns1 + (long)cg * HW + gh * 96 + gw]
                  : in2[(long)n * ns2 + (long)(cg - cin1) * HW + gh * 96 + gw];
            }
            in_s[ci][r][c] = v;
        }
        for (int idx = tid; idx < 1152; idx += 256) {       // 8*9*16
            int ci = idx / 144, rem = idx % 144;
            int tap = rem / 16, co = rem & 15;
            w_s[ci][tap][co] = wgt[((long)(co0 + co) * cin + ci0 + ci) * 9 + tap];
        }
        __syncthreads();
        #pragma unroll 2
        for (int ci = 0; ci < 8; ++ci) {
            #pragma unroll
            for (int tap = 0; tap < 9; ++tap) {
                const int ky = tap / 3, kx = tap % 3;
                float wv[16];
                #pragma unroll
                for (int q = 0; q < 4; ++q) {
                    float4 w4 = *reinterpret_cast<const float4*>(&w_s[ci][tap][q * 4]);
                    wv[q*4+0] = w4.x; wv[q*4+1] = w4.y; wv[q*4+2] = w4.z; wv[q*4+3] = w4.w;
                }
                #pragma unroll
                for (int j = 0; j < 3; ++j) {
                    float iv = in_s[ci][r_[j] + ky][c_[j] + kx];
                    #pragma unroll
                    for (int co = 0; co < 16; ++co) acc[co][j] += wv[co] * iv;
                }
            }
        }
        __syncthreads();
    }

    #pragma unroll
    for (int co = 0; co < 16; ++co) {
        const int cg = co0 + co;
        float b = bias ? bias[cg] : 0.f;
        #pragma unroll
        for (int j = 0; j < 3; ++j) {
            float v = acc[co][j] + b;
            if (bng) {
                v = v * bng[cg] + bnb[cg];
                v = (v >= 0.f) ? v : pra[cg] * v;
            }
            out[(long)n * nso + (long)cg * HW + (h0 + r_[j]) * 96 + c_[j]] = v;
        }
    }
}

// ---------------------------------------------------------------------------
// pool_to_3x3 for x1 (from xd ch 0..127) and y1 (from y ch 0..127)
// one block per (c, n, which); 9 bins of 32x32 means
// ---------------------------------------------------------------------------
__global__ __launch_bounds__(256) void pool_kernel(
    const float* __restrict__ xd, const float* __restrict__ y,
    float* __restrict__ gl, float* __restrict__ py)
{
    const int c = blockIdx.x, n = blockIdx.y, which = blockIdx.z;
    const int tid = threadIdx.x;
    const float* src = (which == 0) ? (xd + ((long)n * 256 + c) * HW)
                                    : (y  + ((long)n * 256 + c) * HW);
    float local[9];
    #pragma unroll
    for (int k = 0; k < 9; ++k) local[k] = 0.f;
    for (int i = tid; i < HW; i += 256) {
        int h = i / 96, w = i % 96;
        local[(h / 32) * 3 + (w / 32)] += src[i];
    }
    __shared__ float red[9][4];
    const int wv = tid >> 6, lane = tid & 63;
    #pragma unroll
    for (int k = 0; k < 9; ++k) {
        float v = local[k];
        for (int off = 32; off > 0; off >>= 1) v += __shfl_down(v, off, 64);
        if (lane == 0) red[k][wv] = v;
    }
    __syncthreads();
    if (tid < 9) {
        float s = (red[tid][0] + red[tid][1] + red[tid][2] + red[tid][3]) * (1.f / 1024.f);
        float* dst = (which == 0) ? gl : py;
        dst[((long)n * 128 + c) * 9 + tid] = s;
    }
}

// ---------------------------------------------------------------------------
// attention + kc: per (n,c) thread. py[n] staged in LDS for the 128x128 matvec
// ---------------------------------------------------------------------------
__global__ __launch_bounds__(128) void attkc_kernel(
    const float* __restrict__ gl, const float* __restrict__ py,
    const float* __restrict__ w_ce, const float* __restrict__ w_gd,
    const float* __restrict__ bng, const float* __restrict__ bnb,
    const float* __restrict__ w_kc, const float* __restrict__ b_kc,
    float* __restrict__ kc)
{
    const int n = blockIdx.x, c = threadIdx.x;
    __shared__ float py_s[128][9];
    #pragma unroll
    for (int k = 0; k < 9; ++k) py_s[c][k] = py[((long)n * 128 + c) * 9 + k];
    __syncthreads();
    float g[9];
    #pragma unroll
    for (int k = 0; k < 9; ++k) g[k] = gl[((long)n * 128 + c) * 9 + k];
    float t[5];
    #pragma unroll
    for (int l = 0; l < 5; ++l) {
        float s = 0.f;
        #pragma unroll
        for (int k = 0; k < 9; ++k) s += g[k] * w_ce[l * 9 + k];
        s = s * bng[c] + bnb[c];
        t[l] = s > 0.f ? s : 0.f;
    }
    float att[9];
    #pragma unroll
    for (int k = 0; k < 9; ++k) {
        float s = 0.f;
        #pragma unroll
        for (int l = 0; l < 5; ++l) s += t[l] * w_gd[k * 5 + l];
        att[k] = 1.f / (1.f + expf(-s));
    }
    float kc0[9];
    float bk = b_kc[c];
    #pragma unroll
    for (int k = 0; k < 9; ++k) kc0[k] = bk;
    for (int c2 = 0; c2 < 128; ++c2) {
        float wv = w_kc[c * 128 + c2];
        #pragma unroll
        for (int k = 0; k < 9; ++k) kc0[k] += wv * py_s[c2][k];
    }
    #pragma unroll
    for (int k = 0; k < 9; ++k)
        kc[((long)n * 128 + c) * 9 + k] = kc0[k] * att[k];
}

// ---------------------------------------------------------------------------
// channel_after: depthwise 3x3 with per-(n,c) kernel kc[n,c,0..8], zero pad
// ---------------------------------------------------------------------------
__global__ __launch_bounds__(256) void channel_kernel(
    const float* __restrict__ xd, const float* __restrict__ kc,
    float* __restrict__ chbuf)
{
    const int c = blockIdx.x, n = blockIdx.y;
    const int tid = threadIdx.x;
    const float* src = xd + ((long)n * 256 + c) * HW;
    __shared__ float plane[HW];
    for (int i = tid; i < HW; i += 256) plane[i] = src[i];
    float k9[9];
    #pragma unroll
    for (int k = 0; k < 9; ++k) k9[k] = kc[((long)n * 128 + c) * 9 + k];
    __syncthreads();
    for (int i = tid; i < HW; i += 256) {
        int h = i / 96, w = i % 96;
        float acc = 0.f;
        #pragma unroll
        for (int ky = 0; ky < 3; ++ky)
            #pragma unroll
            for (int kx = 0; kx < 3; ++kx) {
                int hh = h + ky - 1, ww = w + kx - 1;
                if (hh >= 0 && hh < 96 && ww >= 0 && ww < 96)
                    acc += k9[ky * 3 + kx] * plane[hh * 96 + ww];
            }
        chbuf[((long)n * 128 + c) * HW + i] = acc;
    }
}

// ---------------------------------------------------------------------------
// ks = 1x1 conv 128->9 on ks_mid
// ---------------------------------------------------------------------------
__global__ __launch_bounds__(256) void ks_kernel(
    const float* __restrict__ ksmid, const float* __restrict__ w_ks2,
    const float* __restrict__ b_ks2, float* __restrict__ ks)
{
    __shared__ float w_s[9 * 128];
    const int tid = threadIdx.x;
    for (int i = tid; i < 1152; i += 256) w_s[i] = w_ks2[i];
    __syncthreads();
    const int p = blockIdx.x * 256 + tid;
    const int n = blockIdx.y;
    float acc[9];
    #pragma unroll
    for (int k = 0; k < 9; ++k) acc[k] = b_ks2[k];
    for (int c = 0; c < 128; ++c) {
        float v = ksmid[((long)n * 128 + c) * HW + p];
        #pragma unroll
        for (int k = 0; k < 9; ++k) acc[k] += w_s[k * 128 + c] * v;
    }
    #pragma unroll
    for (int k = 0; k < 9; ++k) ks[((long)n * 9 + k) * HW + p] = acc[k];
}

// ---------------------------------------------------------------------------
// ksp = 3x3 conv x2 (128 ch) -> 1 ch, no bias, pad 1
// ---------------------------------------------------------------------------
__global__ __launch_bounds__(256) void ksp_kernel(
    const float* __restrict__ xd, const float* __restrict__ w_sp1,
    float* __restrict__ ksp)
{
    const int h0 = blockIdx.x * 8;
    const int n  = blockIdx.y;
    const int tid = threadIdx.x;
    __shared__ float in_s[8][10][98];
    __shared__ float w_s[1152];
    for (int i = tid; i < 1152; i += 256) w_s[i] = w_sp1[i];
    float acc[3] = {0.f, 0.f, 0.f};
    int r_[3], c_[3];
    #pragma unroll
    for (int j = 0; j < 3; ++j) { int px = tid + j * 256; r_[j] = px / 96; c_[j] = px % 96; }
    for (int ci0 = 0; ci0 < 128; ci0 += 8) {
        __syncthreads();
        for (int idx = tid; idx < 7840; idx += 256) {
            int ci = idx / 980, rem = idx % 980;
            int r = rem / 98, c = rem % 98;
            int gh = h0 + r - 1, gw = c - 1;
            float v = 0.f;
            if (gh >= 0 && gh < 96 && gw >= 0 && gw < 96)
                v = xd[((long)n * 256 + 128 + ci0 + ci) * HW + gh * 96 + gw];
            in_s[ci][r][c] = v;
        }
        __syncthreads();
        #pragma unroll 2
        for (int ci = 0; ci < 8; ++ci)
            #pragma unroll
            for (int tap = 0; tap < 9; ++tap) {
                const int ky = tap / 3, kx = tap % 3;
                float wv = w_s[(ci0 + ci) * 9 + tap];
                #pragma unroll
                for (int j = 0; j < 3; ++j)
                    acc[j] += wv * in_s[ci][r_[j] + ky][c_[j] + kx];
            }
    }
    #pragma unroll
    for (int j = 0; j < 3; ++j)
        ksp[(long)n * HW + (h0 + r_[j]) * 96 + c_[j]] = acc[j];
}

// ---------------------------------------------------------------------------
// sp = sigmoid(conv3x3([avg3x3(ksp), max3x3(ksp)], w_sp, pad=1))
// avg/max include zero padding (patches of the zero-padded ksp)
// ---------------------------------------------------------------------------
__global__ __launch_bounds__(256) void sp_kernel(
    const float* __restrict__ ksp, const float* __restrict__ w_sp,
    float* __restrict__ sp)
{
    const int p = blockIdx.x * 256 + threadIdx.x;
    const int n = blockIdx.y;
    const int h = p / 96, w = p % 96;
    const float* kp = ksp + (long)n * HW;
    float acc = 0.f;
    #pragma unroll
    for (int dy = 0; dy < 3; ++dy)
        #pragma unroll
        for (int dx = 0; dx < 3; ++dx) {
            int hh = h + dy - 1, ww = w + dx - 1;
            if (hh < 0 || hh >= 96 || ww < 0 || ww >= 96) continue;  // avg=mx=0 outside
            float s = 0.f, m = -1e30f;
            #pragma unroll
            for (int iy = 0; iy < 3; ++iy)
                #pragma unroll
                for (int ix = 0; ix < 3; ++ix) {
                    int h2 = hh + iy - 1, w2 = ww + ix - 1;
                    float v = (h2 >= 0 && h2 < 96 && w2 >= 0 && w2 < 96) ? kp[h2 * 96 + w2] : 0.f;
                    s += v; m = fmaxf(m, v);
                }
            acc += w_sp[dy * 3 + dx] * (s * (1.f / 9.f)) + w_sp[9 + dy * 3 + dx] * m;
        }
    sp[(long)n * HW + p] = 1.f / (1.f + expf(-acc));
}

// ---------------------------------------------------------------------------
// spatial_after — NOTE: the reference's unfold_x is a RAW RESHAPE
// (n, c2*9, h*w) -> (n, h, w, c2, 9), i.e. element [n,h',w',c',k'] is
// patches-flat index f = ((h'*96+w')*128+c')*9+k' decoded in (c,k,h,w) order.
// We reproduce that scrambled gather exactly.
// ---------------------------------------------------------------------------
__global__ __launch_bounds__(256) void spatial_kernel(
    const float* __restrict__ xd, const float* __restrict__ ks,
    const float* __restrict__ sp, float* __restrict__ spbuf)
{
    const int gid = blockIdx.x * 256 + threadIdx.x;   // < 8*128*9216
    const int p = gid % HW;
    const int t = gid / HW;
    const int c = t % 128;
    const int n = t / 128;
    const float spv = sp[(long)n * HW + p];
    float kv[9];
    #pragma unroll
    for (int k = 0; k < 9; ++k) kv[k] = ks[((long)n * 9 + k) * HW + p] * spv;
    const float* x2 = xd + ((long)n * 256 + 128) * HW;
    const int basef = (p * 128 + c) * 9;
    float acc = 0.f;
    #pragma unroll
    for (int kq = 0; kq < 9; ++kq) {
        int f = basef + kq;
        int cc  = f / 82944;            // 128*9*... = 9*9216
        int rem = f - cc * 82944;
        int kk  = rem / 9216;
        int r2  = rem - kk * 9216;
        int hh = r2 / 96 + kk / 3 - 1;
        int ww = r2 % 96 + kk % 3 - 1;
        float v = (hh >= 0 && hh < 96 && ww >= 0 && ww < 96) ? x2[cc * HW + hh * 96 + ww] : 0.f;
        acc += v * kv[kq];
    }
    spbuf[((long)n * 128 + c) * HW + p] = acc;
}

// ---------------------------------------------------------------------------
extern "C" void kernel_launch(void* const* d_in, const int* in_sizes, int n_in,
                              void* d_out, int out_size, void* d_ws, size_t ws_size,
                              hipStream_t stream)
{
    const float* x      = (const float*)d_in[0];
    const float* y      = (const float*)d_in[1];
    const float* w_down = (const float*)d_in[2];
    const float* b_down = (const float*)d_in[3];
    const float* w_ce   = (const float*)d_in[4];
    const float* w_gd   = (const float*)d_in[5];
    const float* bn_g   = (const float*)d_in[6];
    const float* bn_b   = (const float*)d_in[7];
    const float* w_kc   = (const float*)d_in[8];
    const float* b_kc   = (const float*)d_in[9];
    const float* w_ks1  = (const float*)d_in[10];
    const float* b_ks1  = (const float*)d_in[11];
    const float* w_ks2  = (const float*)d_in[12];
    const float* b_ks2  = (const float*)d_in[13];
    const float* w_sp1  = (const float*)d_in[14];
    const float* w_sp   = (const float*)d_in[15];
    const float* w_fb   = (const float*)d_in[16];
    const float* b_fb   = (const float*)d_in[17];
    const float* w_fuse = (const float*)d_in[18];
    const float* bn2_g  = (const float*)d_in[19];
    const float* bn2_b  = (const float*)d_in[20];
    const float* prelu  = (const float*)d_in[21];
    float* out = (float*)d_out;
    float* ws  = (float*)d_ws;

    const long HWl = HW;
    float* xd    = ws;                        // 8*256*9216
    float* chbuf = xd    + 8L * 256 * HWl;    // 8*128*9216  (channel_after)
    float* spbuf = chbuf + 8L * 128 * HWl;    // 8*128*9216  (spatial_after; aliases ks_mid)
    float* r1    = spbuf + 8L * 128 * HWl;    // 8*256*9216
    float* ks    = r1    + 8L * 256 * HWl;    // 8*9*9216
    float* ksp   = ks    + 8L * 9 * HWl;      // 8*9216
    float* spb   = ksp   + 8L * HWl;          // 8*9216
    float* gl    = spb   + 8L * HWl;          // 8*128*9
    float* py    = gl    + 8L * 128 * 9;      // 8*128*9
    float* kc    = py    + 8L * 128 * 9;      // 8*128*9
    float* ksmid = spbuf;                     // dead before spatial_after written

    // 1. down conv
    conv1x1_kernel<<<dim3(144, 4, 8), 256, 0, stream>>>(x, w_down, b_down, xd);
    // 2. pools (x1 from xd, y1 from y)
    pool_kernel<<<dim3(128, 8, 2), 256, 0, stream>>>(xd, y, gl, py);
    // 3. attention + kc
    attkc_kernel<<<dim3(8), 128, 0, stream>>>(gl, py, w_ce, w_gd, bn_g, bn_b, w_kc, b_kc, kc);
    // 4. channel_after
    channel_kernel<<<dim3(128, 8), 256, 0, stream>>>(xd, kc, chbuf);
    // 5. ks_mid = conv3x3(y2, w_ks1)+b
    conv3x3_kernel<<<dim3(12, 8, 8), 256, 0, stream>>>(
        y + 128L * HWl, 128, 256L * HWl, nullptr, 0, 0L,
        w_ks1, b_ks1, ksmid, 128L * HWl, nullptr, nullptr, nullptr);
    // 6. ks = 1x1(ks_mid)
    ks_kernel<<<dim3(36, 8), 256, 0, stream>>>(ksmid, w_ks2, b_ks2, ks);
    // 7. ksp, sp
    ksp_kernel<<<dim3(12, 8), 256, 0, stream>>>(xd, w_sp1, ksp);
    sp_kernel<<<dim3(36, 8), 256, 0, stream>>>(ksp, w_sp, spb);
    // 8. spatial_after (overwrites ksmid region — ks already extracted)
    spatial_kernel<<<dim3(36864), 256, 0, stream>>>(xd, ks, spb, spbuf);
    // 9. r1 = conv3x3([chbuf, spbuf], w_fb)+b
    conv3x3_kernel<<<dim3(12, 16, 8), 256, 0, stream>>>(
        chbuf, 128, 128L * HWl, spbuf, 128, 128L * HWl,
        w_fb, b_fb, r1, 256L * HWl, nullptr, nullptr, nullptr);
    // 10. o = prelu(bn(conv3x3([xd, r1], w_fuse)))
    conv3x3_kernel<<<dim3(12, 16, 8), 256, 0, stream>>>(
        xd, 256, 256L * HWl, r1, 256, 256L * HWl,
        w_fuse, nullptr, out, 256L * HWl, bn2_g, bn2_b, prelu);
}

// Round 2
// 1177.866 us; speedup vs baseline: 5.0033x; 5.0033x over previous
//
#include <hip/hip_runtime.h>
#include <hip/hip_bf16.h>
#include <math.h>

#define HW 9216
#define IMG 96

typedef __bf16 bf16x8 __attribute__((ext_vector_type(8)));
typedef float  f32x4  __attribute__((ext_vector_type(4)));

// ---------------------------------------------------------------------------
// 1x1 conv (GEMM): xd[n,co,p] = b[co] + sum_ci w[co,ci] * x[n,ci,p]   (fp32)
// ---------------------------------------------------------------------------
__global__ __launch_bounds__(256) void conv1x1_kernel(
    const float* __restrict__ in, const float* __restrict__ wgt,
    const float* __restrict__ bias, float* __restrict__ out)
{
    __shared__ float a_s[16][68];
    __shared__ float b_s[16][64];
    const int pb  = blockIdx.x * 64;
    const int co0 = blockIdx.y * 64;
    const int n   = blockIdx.z;
    const int tid = threadIdx.x;
    const int tx = tid & 15, ty = tid >> 4;
    float acc[4][4];
    #pragma unroll
    for (int i = 0; i < 4; ++i)
        #pragma unroll
        for (int j = 0; j < 4; ++j) acc[i][j] = 0.f;

    for (int k0 = 0; k0 < 512; k0 += 16) {
        #pragma unroll
        for (int t = 0; t < 4; ++t) {
            int idx = tid + t * 256;
            int c = idx >> 4, k = idx & 15;
            a_s[k][c] = wgt[(co0 + c) * 512 + k0 + k];
        }
        #pragma unroll
        for (int t = 0; t < 4; ++t) {
            int idx = tid + t * 256;
            int k = idx >> 6, p = idx & 63;
            b_s[k][p] = in[((long)n * 512 + k0 + k) * HW + pb + p];
        }
        __syncthreads();
        #pragma unroll
        for (int kk = 0; kk < 16; ++kk) {
            float4 av4 = *reinterpret_cast<const float4*>(&a_s[kk][ty * 4]);
            float4 bv4 = *reinterpret_cast<const float4*>(&b_s[kk][tx * 4]);
            float a[4] = {av4.x, av4.y, av4.z, av4.w};
            float b[4] = {bv4.x, bv4.y, bv4.z, bv4.w};
            #pragma unroll
            for (int i = 0; i < 4; ++i)
                #pragma unroll
                for (int j = 0; j < 4; ++j)
                    acc[i][j] += a[i] * b[j];
        }
        __syncthreads();
    }
    #pragma unroll
    for (int i = 0; i < 4; ++i) {
        int co = co0 + ty * 4 + i;
        float bb = bias[co];
        #pragma unroll
        for (int j = 0; j < 4; ++j)
            out[((long)n * 256 + co) * HW + pb + tx * 4 + j] = acc[i][j] + bb;
    }
}

// ---------------------------------------------------------------------------
// NCHW fp32 -> NHWC bf16 transpose/convert. src pre-offset to channel 0 of the
// region; dst pre-offset to its channel slot. grid (HW/64, cin/32, N)
// ---------------------------------------------------------------------------
__global__ __launch_bounds__(256) void nchw2nhwc_kernel(
    const float* __restrict__ src, long n_stride_src, int cin_blocks_unused,
    __hip_bfloat16* __restrict__ dst, int dst_stride)
{
    __shared__ float tile[32][65];
    const int px0 = blockIdx.x * 64;
    const int c0  = blockIdx.y * 32;
    const int n   = blockIdx.z;
    const int tid = threadIdx.x;
    const int tx = tid & 63, ty = tid >> 6;
    #pragma unroll
    for (int i = 0; i < 8; ++i)
        tile[ty + i * 4][tx] = src[n * n_stride_src + (long)(c0 + ty + i * 4) * HW + px0 + tx];
    __syncthreads();
    const int ci = tid & 31, pxl = tid >> 5;
    #pragma unroll
    for (int j = 0; j < 8; ++j) {
        int px = pxl + j * 8;
        dst[((long)n * HW + px0 + px) * dst_stride + c0 + ci] = __float2bfloat16(tile[c0 ? ci : ci][px]);
    }
}

// ---------------------------------------------------------------------------
// weight convert: dst[t][co][ci] = bf16(src[co][ci][t])
// ---------------------------------------------------------------------------
__global__ __launch_bounds__(256) void wconv_kernel(
    const float* __restrict__ src, __hip_bfloat16* __restrict__ dst,
    int cout, int cin)
{
    int idx = blockIdx.x * 256 + threadIdx.x;
    if (idx >= cout * cin) return;
    int co = idx / cin, ci = idx % cin;
    #pragma unroll
    for (int t = 0; t < 9; ++t)
        dst[((long)t * cout + co) * cin + ci] = __float2bfloat16(src[(long)idx * 9 + t]);
}

// ---------------------------------------------------------------------------
// MFMA implicit-GEMM 3x3 conv, pad=1, bf16 in, fp32 acc.
// in_nhwc [N][9216][CIN] bf16 ; w_t [9][cout][CIN] bf16 (tap-major)
// block: 256 thr = 4 waves; tile 64 co x 4 rows x 96 cols; ci-chunk 32.
// wave w computes row (h0+w): 4 M-frags x 6 N-frags, mfma 16x16x32.
// ---------------------------------------------------------------------------
template<int CIN>
__global__ __launch_bounds__(256, 2) void mfma_conv3x3(
    const __hip_bfloat16* __restrict__ in_nhwc,
    const __hip_bfloat16* __restrict__ w_t,
    const float* __restrict__ bias,
    float* __restrict__ out_nchw, long nchw_nstride,
    __hip_bfloat16* __restrict__ out_nhwc, int nhwc_stride,
    int cout,
    const float* __restrict__ bng, const float* __restrict__ bnb,
    const float* __restrict__ pra)
{
    const int h0  = blockIdx.x * 4;
    const int cob = blockIdx.y * 64;
    const int n   = blockIdx.z;
    const int tid = threadIdx.x;
    const int wave = tid >> 6;
    const int lane = tid & 63;
    const int l16 = lane & 15, lg = lane >> 4;

    __shared__ __align__(16) __hip_bfloat16 in_s[6][98][32];  // 37632 B
    __shared__ __align__(16) __hip_bfloat16 w_s[3][64][32];   // 12288 B

    f32x4 acc[4][6];
    #pragma unroll
    for (int m = 0; m < 4; ++m)
        #pragma unroll
        for (int nf = 0; nf < 6; ++nf) acc[m][nf] = (f32x4){0.f, 0.f, 0.f, 0.f};

    const long pix_base = (long)n * HW;

    for (int ci0 = 0; ci0 < CIN; ci0 += 32) {
        __syncthreads();   // protect in_s/w_s from previous iteration's reads
        // stage input stripe: rows h0-1..h0+4, cols -1..96, 32 ci -> 588 px * 4 segs
        for (int seg = tid; seg < 2352; seg += 256) {
            int pix = seg >> 2, q = seg & 3;
            int r = pix / 98, c = pix % 98;
            int h = h0 - 1 + r, w = c - 1;
            uint4 v = {0u, 0u, 0u, 0u};
            if (h >= 0 && h < IMG && w >= 0 && w < IMG)
                v = *reinterpret_cast<const uint4*>(
                        &in_nhwc[(pix_base + (long)h * IMG + w) * CIN + ci0 + q * 8]);
            *reinterpret_cast<uint4*>(&in_s[r][c][q * 8]) = v;
        }
        #pragma unroll
        for (int g = 0; g < 3; ++g) {                 // g == ky
            if (g > 0) __syncthreads();               // protect w_s
            for (int seg = tid; seg < 768; seg += 256) {
                int t3 = seg >> 8, rem = seg & 255;
                int co = rem >> 2, q = rem & 3;
                uint4 v = *reinterpret_cast<const uint4*>(
                    &w_t[((long)(g * 3 + t3) * cout + cob + co) * CIN + ci0 + q * 8]);
                *reinterpret_cast<uint4*>(&w_s[t3][co][q * 8]) = v;
            }
            __syncthreads();
            #pragma unroll
            for (int kx = 0; kx < 3; ++kx) {
                bf16x8 a[4];
                #pragma unroll
                for (int m = 0; m < 4; ++m)
                    a[m] = *reinterpret_cast<const bf16x8*>(&w_s[kx][m * 16 + l16][lg * 8]);
                #pragma unroll
                for (int nf = 0; nf < 6; ++nf) {
                    bf16x8 b = *reinterpret_cast<const bf16x8*>(
                        &in_s[wave + g][nf * 16 + l16 + kx][lg * 8]);
                    #pragma unroll
                    for (int m = 0; m < 4; ++m)
                        acc[m][nf] = __builtin_amdgcn_mfma_f32_16x16x32_bf16(
                            a[m], b, acc[m][nf], 0, 0, 0);
                }
            }
        }
    }

    // epilogue
    const int hrow = h0 + wave;
    #pragma unroll
    for (int m = 0; m < 4; ++m) {
        const int co = cob + m * 16 + lg * 4;
        float bs[4], g4[4], b4[4], p4[4];
        #pragma unroll
        for (int r = 0; r < 4; ++r) bs[r] = bias ? bias[co + r] : 0.f;
        if (bng) {
            #pragma unroll
            for (int r = 0; r < 4; ++r) { g4[r] = bng[co + r]; b4[r] = bnb[co + r]; p4[r] = pra[co + r]; }
        }
        #pragma unroll
        for (int nf = 0; nf < 6; ++nf) {
            const int wcol = nf * 16 + l16;
            const long px = (long)hrow * IMG + wcol;
            float v[4];
            #pragma unroll
            for (int r = 0; r < 4; ++r) {
                v[r] = acc[m][nf][r] + bs[r];
                if (bng) {
                    v[r] = v[r] * g4[r] + b4[r];
                    v[r] = (v[r] >= 0.f) ? v[r] : p4[r] * v[r];
                }
            }
            if (out_nchw) {
                #pragma unroll
                for (int r = 0; r < 4; ++r)
                    out_nchw[(long)n * nchw_nstride + (long)(co + r) * HW + px] = v[r];
            }
            if (out_nhwc) {
                union { __hip_bfloat16 h[4]; uint2 u; } pk;
                #pragma unroll
                for (int r = 0; r < 4; ++r) pk.h[r] = __float2bfloat16(v[r]);
                *reinterpret_cast<uint2*>(&out_nhwc[(pix_base + px) * nhwc_stride + co]) = pk.u;
            }
        }
    }
}

// ---------------------------------------------------------------------------
// pool_to_3x3 for x1 (xd ch 0..127) and y1 (y ch 0..127)
// ---------------------------------------------------------------------------
__global__ __launch_bounds__(256) void pool_kernel(
    const float* __restrict__ xd, const float* __restrict__ y,
    float* __restrict__ gl, float* __restrict__ py)
{
    const int c = blockIdx.x, n = blockIdx.y, which = blockIdx.z;
    const int tid = threadIdx.x;
    const float* src = (which == 0) ? (xd + ((long)n * 256 + c) * HW)
                                    : (y  + ((long)n * 256 + c) * HW);
    float local[9];
    #pragma unroll
    for (int k = 0; k < 9; ++k) local[k] = 0.f;
    for (int i = tid; i < HW; i += 256) {
        int h = i / 96, w = i % 96;
        local[(h / 32) * 3 + (w / 32)] += src[i];
    }
    __shared__ float red[9][4];
    const int wv = tid >> 6, lane = tid & 63;
    #pragma unroll
    for (int k = 0; k < 9; ++k) {
        float v = local[k];
        for (int off = 32; off > 0; off >>= 1) v += __shfl_down(v, off, 64);
        if (lane == 0) red[k][wv] = v;
    }
    __syncthreads();
    if (tid < 9) {
        float s = (red[tid][0] + red[tid][1] + red[tid][2] + red[tid][3]) * (1.f / 1024.f);
        float* dst = (which == 0) ? gl : py;
        dst[((long)n * 128 + c) * 9 + tid] = s;
    }
}

// ---------------------------------------------------------------------------
__global__ __launch_bounds__(128) void attkc_kernel(
    const float* __restrict__ gl, const float* __restrict__ py,
    const float* __restrict__ w_ce, const float* __restrict__ w_gd,
    const float* __restrict__ bng, const float* __restrict__ bnb,
    const float* __restrict__ w_kc, const float* __restrict__ b_kc,
    float* __restrict__ kc)
{
    const int n = blockIdx.x, c = threadIdx.x;
    __shared__ float py_s[128][9];
    #pragma unroll
    for (int k = 0; k < 9; ++k) py_s[c][k] = py[((long)n * 128 + c) * 9 + k];
    __syncthreads();
    float g[9];
    #pragma unroll
    for (int k = 0; k < 9; ++k) g[k] = gl[((long)n * 128 + c) * 9 + k];
    float t[5];
    #pragma unroll
    for (int l = 0; l < 5; ++l) {
        float s = 0.f;
        #pragma unroll
        for (int k = 0; k < 9; ++k) s += g[k] * w_ce[l * 9 + k];
        s = s * bng[c] + bnb[c];
        t[l] = s > 0.f ? s : 0.f;
    }
    float att[9];
    #pragma unroll
    for (int k = 0; k < 9; ++k) {
        float s = 0.f;
        #pragma unroll
        for (int l = 0; l < 5; ++l) s += t[l] * w_gd[k * 5 + l];
        att[k] = 1.f / (1.f + expf(-s));
    }
    float kc0[9];
    float bk = b_kc[c];
    #pragma unroll
    for (int k = 0; k < 9; ++k) kc0[k] = bk;
    for (int c2 = 0; c2 < 128; ++c2) {
        float wv = w_kc[c * 128 + c2];
        #pragma unroll
        for (int k = 0; k < 9; ++k) kc0[k] += wv * py_s[c2][k];
    }
    #pragma unroll
    for (int k = 0; k < 9; ++k)
        kc[((long)n * 128 + c) * 9 + k] = kc0[k] * att[k];
}

// ---------------------------------------------------------------------------
// channel_after -> catsrc channels 0..127 (n-stride 256*HW)
// ---------------------------------------------------------------------------
__global__ __launch_bounds__(256) void channel_kernel(
    const float* __restrict__ xd, const float* __restrict__ kc,
    float* __restrict__ catsrc)
{
    const int c = blockIdx.x, n = blockIdx.y;
    const int tid = threadIdx.x;
    const float* src = xd + ((long)n * 256 + c) * HW;
    __shared__ float plane[HW];
    for (int i = tid; i < HW; i += 256) plane[i] = src[i];
    float k9[9];
    #pragma unroll
    for (int k = 0; k < 9; ++k) k9[k] = kc[((long)n * 128 + c) * 9 + k];
    __syncthreads();
    for (int i = tid; i < HW; i += 256) {
        int h = i / 96, w = i % 96;
        float acc = 0.f;
        #pragma unroll
        for (int ky = 0; ky < 3; ++ky)
            #pragma unroll
            for (int kx = 0; kx < 3; ++kx) {
                int hh = h + ky - 1, ww = w + kx - 1;
                if (hh >= 0 && hh < 96 && ww >= 0 && ww < 96)
                    acc += k9[ky * 3 + kx] * plane[hh * 96 + ww];
            }
        catsrc[((long)n * 256 + c) * HW + i] = acc;
    }
}

// ---------------------------------------------------------------------------
// ks = 1x1 conv 128->9 on ksmid (= catsrc ch 128..255, n-stride 256*HW)
// ---------------------------------------------------------------------------
__global__ __launch_bounds__(256) void ks_kernel(
    const float* __restrict__ ksmid, const float* __restrict__ w_ks2,
    const float* __restrict__ b_ks2, float* __restrict__ ks)
{
    __shared__ float w_s[9 * 128];
    const int tid = threadIdx.x;
    for (int i = tid; i < 1152; i += 256) w_s[i] = w_ks2[i];
    __syncthreads();
    const int p = blockIdx.x * 256 + tid;
    const int n = blockIdx.y;
    float acc[9];
    #pragma unroll
    for (int k = 0; k < 9; ++k) acc[k] = b_ks2[k];
    for (int c = 0; c < 128; ++c) {
        float v = ksmid[((long)n * 256 + c) * HW + p];
        #pragma unroll
        for (int k = 0; k < 9; ++k) acc[k] += w_s[k * 128 + c] * v;
    }
    #pragma unroll
    for (int k = 0; k < 9; ++k) ks[((long)n * 9 + k) * HW + p] = acc[k];
}

// ---------------------------------------------------------------------------
__global__ __launch_bounds__(256) void ksp_kernel(
    const float* __restrict__ xd, const float* __restrict__ w_sp1,
    float* __restrict__ ksp)
{
    const int h0 = blockIdx.x * 8;
    const int n  = blockIdx.y;
    const int tid = threadIdx.x;
    __shared__ float in_s[8][10][98];
    __shared__ float w_s[1152];
    for (int i = tid; i < 1152; i += 256) w_s[i] = w_sp1[i];
    float acc[3] = {0.f, 0.f, 0.f};
    int r_[3], c_[3];
    #pragma unroll
    for (int j = 0; j < 3; ++j) { int px = tid + j * 256; r_[j] = px / 96; c_[j] = px % 96; }
    for (int ci0 = 0; ci0 < 128; ci0 += 8) {
        __syncthreads();
        for (int idx = tid; idx < 7840; idx += 256) {
            int ci = idx / 980, rem = idx % 980;
            int r = rem / 98, c = rem % 98;
            int gh = h0 + r - 1, gw = c - 1;
            float v = 0.f;
            if (gh >= 0 && gh < 96 && gw >= 0 && gw < 96)
                v = xd[((long)n * 256 + 128 + ci0 + ci) * HW + gh * 96 + gw];
            in_s[ci][r][c] = v;
        }
        __syncthreads();
        #pragma unroll 2
        for (int ci = 0; ci < 8; ++ci)
            #pragma unroll
            for (int tap = 0; tap < 9; ++tap) {
                const int ky = tap / 3, kx = tap % 3;
                float wv = w_s[(ci0 + ci) * 9 + tap];
                #pragma unroll
                for (int j = 0; j < 3; ++j)
                    acc[j] += wv * in_s[ci][r_[j] + ky][c_[j] + kx];
            }
    }
    #pragma unroll
    for (int j = 0; j < 3; ++j)
        ksp[(long)n * HW + (h0 + r_[j]) * 96 + c_[j]] = acc[j];
}

// ---------------------------------------------------------------------------
__global__ __launch_bounds__(256) void sp_kernel(
    const float* __restrict__ ksp, const float* __restrict__ w_sp,
    float* __restrict__ sp)
{
    const int p = blockIdx.x * 256 + threadIdx.x;
    const int n = blockIdx.y;
    const int h = p / 96, w = p % 96;
    const float* kp = ksp + (long)n * HW;
    float acc = 0.f;
    #pragma unroll
    for (int dy = 0; dy < 3; ++dy)
        #pragma unroll
        for (int dx = 0; dx < 3; ++dx) {
            int hh = h + dy - 1, ww = w + dx - 1;
            if (hh < 0 || hh >= 96 || ww < 0 || ww >= 96) continue;
            float s = 0.f, m = -1e30f;
            #pragma unroll
            for (int iy = 0; iy < 3; ++iy)
                #pragma unroll
                for (int ix = 0; ix < 3; ++ix) {
                    int h2 = hh + iy - 1, w2 = ww + ix - 1;
                    float v = (h2 >= 0 && h2 < 96 && w2 >= 0 && w2 < 96) ? kp[h2 * 96 + w2] : 0.f;
                    s += v; m = fmaxf(m, v);
                }
            acc += w_sp[dy * 3 + dx] * (s * (1.f / 9.f)) + w_sp[9 + dy * 3 + dx] * m;
        }
    sp[(long)n * HW + p] = 1.f / (1.f + expf(-acc));
}

// ---------------------------------------------------------------------------
// spatial_after -> catsrc channels 128..255 (reference's raw-reshape gather)
// ---------------------------------------------------------------------------
__global__ __launch_bounds__(256) void spatial_kernel(
    const float* __restrict__ xd, const float* __restrict__ ks,
    const float* __restrict__ sp, float* __restrict__ catsrc)
{
    const int gid = blockIdx.x * 256 + threadIdx.x;
    const int p = gid % HW;
    const int t = gid / HW;
    const int c = t % 128;
    const int n = t / 128;
    const float spv = sp[(long)n * HW + p];
    float kv[9];
    #pragma unroll
    for (int k = 0; k < 9; ++k) kv[k] = ks[((long)n * 9 + k) * HW + p] * spv;
    const float* x2 = xd + ((long)n * 256 + 128) * HW;
    const int basef = (p * 128 + c) * 9;
    float acc = 0.f;
    #pragma unroll
    for (int kq = 0; kq < 9; ++kq) {
        int f = basef + kq;
        int cc  = f / 82944;
        int rem = f - cc * 82944;
        int kk  = rem / 9216;
        int r2  = rem - kk * 9216;
        int hh = r2 / 96 + kk / 3 - 1;
        int ww = r2 % 96 + kk % 3 - 1;
        float v = (hh >= 0 && hh < 96 && ww >= 0 && ww < 96) ? x2[cc * HW + hh * 96 + ww] : 0.f;
        acc += v * kv[kq];
    }
    catsrc[((long)n * 256 + 128 + c) * HW + p] = acc;
}

// ---------------------------------------------------------------------------
extern "C" void kernel_launch(void* const* d_in, const int* in_sizes, int n_in,
                              void* d_out, int out_size, void* d_ws, size_t ws_size,
                              hipStream_t stream)
{
    const float* x      = (const float*)d_in[0];
    const float* y      = (const float*)d_in[1];
    const float* w_down = (const float*)d_in[2];
    const float* b_down = (const float*)d_in[3];
    const float* w_ce   = (const float*)d_in[4];
    const float* w_gd   = (const float*)d_in[5];
    const float* bn_g   = (const float*)d_in[6];
    const float* bn_b   = (const float*)d_in[7];
    const float* w_kc   = (const float*)d_in[8];
    const float* b_kc   = (const float*)d_in[9];
    const float* w_ks1  = (const float*)d_in[10];
    const float* b_ks1  = (const float*)d_in[11];
    const float* w_ks2  = (const float*)d_in[12];
    const float* b_ks2  = (const float*)d_in[13];
    const float* w_sp1  = (const float*)d_in[14];
    const float* w_sp   = (const float*)d_in[15];
    const float* w_fb   = (const float*)d_in[16];
    const float* b_fb   = (const float*)d_in[17];
    const float* w_fuse = (const float*)d_in[18];
    const float* bn2_g  = (const float*)d_in[19];
    const float* bn2_b  = (const float*)d_in[20];
    const float* prelu  = (const float*)d_in[21];
    float* out = (float*)d_out;
    char* ws = (char*)d_ws;

    const long HWl = HW;
    // --- workspace layout (bytes) ---
    float* xd       = (float*)ws;                                  ws += 8L*256*HWl*4;   // 75.5MB
    float* catsrc   = (float*)ws;                                                        // fp32 [8][256][HW]
    __hip_bfloat16* cat_fuse = (__hip_bfloat16*)catsrc;            ws += 8L*256*HWl*4;   // aliases catsrc (75.5MB)
    __hip_bfloat16* catfb_bf = (__hip_bfloat16*)ws;                ws += 8L*HWl*256*2;   // 37.7MB
    __hip_bfloat16* y2t      = (__hip_bfloat16*)ws;                ws += 8L*HWl*128*2;   // 18.9MB
    __hip_bfloat16* wks1_bf  = (__hip_bfloat16*)ws;                ws += 9L*128*128*2;
    __hip_bfloat16* wfb_bf   = (__hip_bfloat16*)ws;                ws += 9L*256*256*2;
    __hip_bfloat16* wfuse_bf = (__hip_bfloat16*)ws;                ws += 9L*256*512*2;
    float* ks   = (float*)ws;  ws += 8L*9*HWl*4;
    float* ksp  = (float*)ws;  ws += 8L*HWl*4;
    float* spb  = (float*)ws;  ws += 8L*HWl*4;
    float* gl   = (float*)ws;  ws += 8L*128*9*4;
    float* py   = (float*)ws;  ws += 8L*128*9*4;
    float* kc   = (float*)ws;  ws += 8L*128*9*4;
    float* ksmid = catsrc + 128L*HWl;   // catsrc channels 128..255 (n-stride 256*HW)

    // 0. weight conversions (independent)
    wconv_kernel<<<dim3(64),  256, 0, stream>>>(w_ks1,  wks1_bf,  128, 128);
    wconv_kernel<<<dim3(256), 256, 0, stream>>>(w_fb,   wfb_bf,   256, 256);
    wconv_kernel<<<dim3(512), 256, 0, stream>>>(w_fuse, wfuse_bf, 256, 512);
    // 1. down conv (fp32)
    conv1x1_kernel<<<dim3(144, 4, 8), 256, 0, stream>>>(x, w_down, b_down, xd);
    // 2. y2 -> NHWC bf16
    nchw2nhwc_kernel<<<dim3(144, 4, 8), 256, 0, stream>>>(y + 128L*HWl, 256L*HWl, 0, y2t, 128);
    // 3. pools / attention / channel_after
    pool_kernel<<<dim3(128, 8, 2), 256, 0, stream>>>(xd, y, gl, py);
    attkc_kernel<<<dim3(8), 128, 0, stream>>>(gl, py, w_ce, w_gd, bn_g, bn_b, w_kc, b_kc, kc);
    channel_kernel<<<dim3(128, 8), 256, 0, stream>>>(xd, kc, catsrc);
    // 4. ks_mid = mfma conv3x3(y2, w_ks1)+b  -> catsrc ch128..255
    mfma_conv3x3<128><<<dim3(24, 2, 8), 256, 0, stream>>>(
        y2t, wks1_bf, b_ks1, ksmid, 256L*HWl, nullptr, 0, 128, nullptr, nullptr, nullptr);
    // 5. ks = 1x1(ks_mid)
    ks_kernel<<<dim3(36, 8), 256, 0, stream>>>(ksmid, w_ks2, b_ks2, ks);
    // 6. ksp, sp
    ksp_kernel<<<dim3(12, 8), 256, 0, stream>>>(xd, w_sp1, ksp);
    sp_kernel<<<dim3(36, 8), 256, 0, stream>>>(ksp, w_sp, spb);
    // 7. spatial_after -> catsrc ch128..255 (overwrites ksmid; ks extracted)
    spatial_kernel<<<dim3(36864), 256, 0, stream>>>(xd, ks, spb, catsrc);
    // 8. catsrc -> NHWC bf16 (fb input)
    nchw2nhwc_kernel<<<dim3(144, 8, 8), 256, 0, stream>>>(catsrc, 256L*HWl, 0, catfb_bf, 256);
    // 9. xd -> NHWC bf16 into cat_fuse ch0..255 (catsrc now dead; aliasing OK)
    nchw2nhwc_kernel<<<dim3(144, 8, 8), 256, 0, stream>>>(xd, 256L*HWl, 0, cat_fuse, 512);
    // 10. r1 = mfma conv3x3(catfb, w_fb)+b -> cat_fuse ch256..511 (NHWC bf16)
    mfma_conv3x3<256><<<dim3(24, 4, 8), 256, 0, stream>>>(
        catfb_bf, wfb_bf, b_fb, nullptr, 0, cat_fuse + 256, 512, 256, nullptr, nullptr, nullptr);
    // 11. out = prelu(bn(mfma conv3x3(cat_fuse, w_fuse)))
    mfma_conv3x3<512><<<dim3(24, 4, 8), 256, 0, stream>>>(
        cat_fuse, wfuse_bf, nullptr, out, 256L*HWl, nullptr, 0, 256, bn2_g, bn2_b, prelu);
}

// Round 3
// 868.179 us; speedup vs baseline: 6.7880x; 1.3567x over previous
//
#include <hip/hip_runtime.h>
#include <hip/hip_bf16.h>
#include <math.h>

#define HW 9216
#define IMG 96

typedef __bf16 bf16x8 __attribute__((ext_vector_type(8)));
typedef float  f32x4  __attribute__((ext_vector_type(4)));

__device__ __forceinline__ void gload16(const void* g, void* l) {
    __builtin_amdgcn_global_load_lds((const unsigned int*)g, (unsigned int*)l, 16, 0, 0);
}

// ---------------------------------------------------------------------------
// NCHW fp32 -> NHWC bf16 transpose/convert. grid (HW/64, cin/32, N)
// ---------------------------------------------------------------------------
__global__ __launch_bounds__(256) void nchw2nhwc_kernel(
    const float* __restrict__ src, long n_stride_src,
    __hip_bfloat16* __restrict__ dst, int dst_stride)
{
    __shared__ float tile[32][65];
    const int px0 = blockIdx.x * 64;
    const int c0  = blockIdx.y * 32;
    const int n   = blockIdx.z;
    const int tid = threadIdx.x;
    const int tx = tid & 63, ty = tid >> 6;
    #pragma unroll
    for (int i = 0; i < 8; ++i)
        tile[ty + i * 4][tx] = src[n * n_stride_src + (long)(c0 + ty + i * 4) * HW + px0 + tx];
    __syncthreads();
    const int ci = tid & 31, pxl = tid >> 5;
    #pragma unroll
    for (int j = 0; j < 8; ++j) {
        int px = pxl + j * 8;
        dst[((long)n * HW + px0 + px) * dst_stride + c0 + ci] = __float2bfloat16(tile[ci][px]);
    }
}

// ---------------------------------------------------------------------------
// weight convert: dst[t][co][ci] = bf16(src[co][ci][t])
// ---------------------------------------------------------------------------
__global__ __launch_bounds__(256) void wconv_kernel(
    const float* __restrict__ src, __hip_bfloat16* __restrict__ dst,
    int cout, int cin, int taps)
{
    int idx = blockIdx.x * 256 + threadIdx.x;
    if (idx >= cout * cin) return;
    int co = idx / cin, ci = idx % cin;
    for (int t = 0; t < taps; ++t)
        dst[((long)t * cout + co) * cin + ci] = __float2bfloat16(src[(long)idx * taps + t]);
}

// ---------------------------------------------------------------------------
// Unified MFMA implicit-GEMM conv (TAPS=9: 3x3 pad=1; TAPS=1: 1x1), bf16 in,
// fp32 acc. in_nhwc [N][HW][CIN]; w_t [TAPS][cout][CIN].
// Block: 4 waves; tile 64co x 4rows x 96cols; ci-chunk 32.
// 2-phase pipeline: double-buffered LDS, global_load_lds staging with
// precomputed per-thread pointers (OOB -> zeropage), 1 barrier/chunk.
// LDS 16B-slot XOR swizzle (q ^= (idx>>1)&3) on both tensors; sources are
// inverse-swizzled so the async (linear) LDS writes land pre-swizzled.
// ---------------------------------------------------------------------------
template<int CIN, int TAPS>
__global__ __launch_bounds__(256, 2) void mfma_conv(
    const __hip_bfloat16* __restrict__ in_nhwc,
    const __hip_bfloat16* __restrict__ w_t,
    const float* __restrict__ bias,
    float* __restrict__ out_nchw, long nchw_nstride,
    __hip_bfloat16* __restrict__ out_nhwc, int nhwc_stride,
    int cout,
    const float* __restrict__ bng, const float* __restrict__ bnb,
    const float* __restrict__ pra,
    const __hip_bfloat16* __restrict__ zeropage)
{
    constexpr int ROWS = (TAPS == 9) ? 6 : 4;
    constexpr int COLS = (TAPS == 9) ? 98 : 96;
    constexpr int HOFF = (TAPS == 9) ? 1 : 0;
    constexpr int NSEG_IN = ROWS * COLS * 4;        // 2352 / 1536
    constexpr int NSEG_W  = TAPS * 64 * 4;          // 2304 / 256
    constexpr int IN_BYTES = NSEG_IN * 16;
    constexpr int W_BYTES  = NSEG_W * 16;
    constexpr int BUF = IN_BYTES + W_BYTES;         // 74496 / 28672
    constexpr int NCHUNK = CIN / 32;
    constexpr int FULL_IN = NSEG_IN / 256;          // 9 / 6
    constexpr int HAS_TAIL = (NSEG_IN % 256) != 0;  // 1 / 0
    constexpr int IT_IN = FULL_IN + HAS_TAIL;
    constexpr int IT_W  = NSEG_W / 256;             // 9 / 1

    extern __shared__ __align__(16) char lds[];     // 2*BUF bytes

    const int h0   = blockIdx.x * 4;
    const int cob  = blockIdx.y * 64;
    const int n    = blockIdx.z;
    const int tid  = threadIdx.x;
    const int lane = tid & 63;
    const int wave = tid >> 6;
    const int l16  = lane & 15, lg = lane >> 4;

    // ---- per-thread staging pointers (advance by 64B per ci-chunk) ----
    const char* inptr[IT_IN];
    int instep[IT_IN];
    #pragma unroll
    for (int t = 0; t < IT_IN; ++t) {
        int seg = tid + t * 256;
        int s2 = (seg < NSEG_IN) ? seg : 0;
        int pix = s2 >> 2, qp = s2 & 3;
        int r = pix / COLS, c = pix % COLS;
        int h = h0 + r - HOFF, w = c - HOFF;
        int q = qp ^ ((c >> 1) & 3);                 // inverse-swizzled source slot
        bool valid = (h >= 0 && h < IMG && w >= 0 && w < IMG);
        inptr[t] = valid
            ? (const char*)(in_nhwc + ((long)n * HW + h * IMG + w) * CIN + q * 8)
            : (const char*)zeropage;
        instep[t] = valid ? 64 : 0;
    }
    const char* wptr[IT_W];
    #pragma unroll
    for (int t = 0; t < IT_W; ++t) {
        int seg = tid + t * 256;
        int tap = seg >> 8, rem = seg & 255;
        int co = rem >> 2, qp = rem & 3;
        int q = qp ^ ((co >> 1) & 3);
        wptr[t] = (const char*)(w_t + ((long)tap * cout + cob + co) * CIN + q * 8);
    }

    auto stage = [&](int bb) {
        char* ib = lds + bb * BUF;
        char* wb = ib + IN_BYTES;
        #pragma unroll
        for (int t = 0; t < FULL_IN; ++t) {
            int seg = tid + t * 256;
            gload16(inptr[t], ib + seg * 16);
            inptr[t] += instep[t];
        }
        if (HAS_TAIL) {
            int seg = tid + FULL_IN * 256;
            if (seg < NSEG_IN) {
                gload16(inptr[IT_IN - 1], ib + seg * 16);
                inptr[IT_IN - 1] += instep[IT_IN - 1];
            }
        }
        #pragma unroll
        for (int t = 0; t < IT_W; ++t) {
            int seg = tid + t * 256;
            gload16(wptr[t], wb + seg * 16);
            wptr[t] += 64;
        }
    };

    f32x4 acc[4][6];
    #pragma unroll
    for (int m = 0; m < 4; ++m)
        #pragma unroll
        for (int nf = 0; nf < 6; ++nf) acc[m][nf] = (f32x4){0.f, 0.f, 0.f, 0.f};

    const int qa = lg ^ ((l16 >> 1) & 3);
    const int a_off = l16 * 64 + qa * 16;

    stage(0);
    __syncthreads();

    for (int ch = 0; ch < NCHUNK; ++ch) {
        if (ch + 1 < NCHUNK) stage((ch + 1) & 1);
        const char* ib = lds + (ch & 1) * BUF;
        const char* wb = ib + IN_BYTES;
        #pragma unroll
        for (int tap = 0; tap < TAPS; ++tap) {
            const int g = (TAPS == 9) ? tap / 3 : 0;
            const int kx = (TAPS == 9) ? tap % 3 : 0;
            bf16x8 a[4];
            #pragma unroll
            for (int m = 0; m < 4; ++m)
                a[m] = *(const bf16x8*)(wb + tap * 4096 + m * 1024 + a_off);
            #pragma unroll
            for (int nf = 0; nf < 6; ++nf) {
                const int c = nf * 16 + l16 + kx;
                const int qb = lg ^ ((c >> 1) & 3);
                bf16x8 b = *(const bf16x8*)(ib + ((wave + g) * COLS + c) * 64 + qb * 16);
                #pragma unroll
                for (int m = 0; m < 4; ++m)
                    acc[m][nf] = __builtin_amdgcn_mfma_f32_16x16x32_bf16(a[m], b, acc[m][nf], 0, 0, 0);
            }
        }
        __syncthreads();
    }

    // ---- epilogue ----
    const int hrow = h0 + wave;
    #pragma unroll
    for (int m = 0; m < 4; ++m) {
        const int co = cob + m * 16 + lg * 4;
        float bs[4], g4[4], b4[4], p4[4];
        #pragma unroll
        for (int r = 0; r < 4; ++r) bs[r] = bias ? bias[co + r] : 0.f;
        if (bng) {
            #pragma unroll
            for (int r = 0; r < 4; ++r) { g4[r] = bng[co + r]; b4[r] = bnb[co + r]; p4[r] = pra[co + r]; }
        }
        #pragma unroll
        for (int nf = 0; nf < 6; ++nf) {
            const int wcol = nf * 16 + l16;
            const long px = (long)hrow * IMG + wcol;
            float v[4];
            #pragma unroll
            for (int r = 0; r < 4; ++r) {
                v[r] = acc[m][nf][r] + bs[r];
                if (bng) {
                    v[r] = v[r] * g4[r] + b4[r];
                    v[r] = (v[r] >= 0.f) ? v[r] : p4[r] * v[r];
                }
            }
            if (out_nchw) {
                #pragma unroll
                for (int r = 0; r < 4; ++r)
                    out_nchw[(long)n * nchw_nstride + (long)(co + r) * HW + px] = v[r];
            }
            if (out_nhwc) {
                union { __hip_bfloat16 h[4]; uint2 u; } pk;
                #pragma unroll
                for (int r = 0; r < 4; ++r) pk.h[r] = __float2bfloat16(v[r]);
                *reinterpret_cast<uint2*>(&out_nhwc[((long)n * HW + px) * nhwc_stride + co]) = pk.u;
            }
        }
    }
}

// ---------------------------------------------------------------------------
// pool_to_3x3 for x1 (xd ch 0..127) and y1 (y ch 0..127)
// ---------------------------------------------------------------------------
__global__ __launch_bounds__(256) void pool_kernel(
    const float* __restrict__ xd, const float* __restrict__ y,
    float* __restrict__ gl, float* __restrict__ py)
{
    const int c = blockIdx.x, n = blockIdx.y, which = blockIdx.z;
    const int tid = threadIdx.x;
    const float* src = (which == 0) ? (xd + ((long)n * 256 + c) * HW)
                                    : (y  + ((long)n * 256 + c) * HW);
    float local[9];
    #pragma unroll
    for (int k = 0; k < 9; ++k) local[k] = 0.f;
    for (int i = tid; i < HW; i += 256) {
        int h = i / 96, w = i % 96;
        local[(h / 32) * 3 + (w / 32)] += src[i];
    }
    __shared__ float red[9][4];
    const int wv = tid >> 6, lane = tid & 63;
    #pragma unroll
    for (int k = 0; k < 9; ++k) {
        float v = local[k];
        for (int off = 32; off > 0; off >>= 1) v += __shfl_down(v, off, 64);
        if (lane == 0) red[k][wv] = v;
    }
    __syncthreads();
    if (tid < 9) {
        float s = (red[tid][0] + red[tid][1] + red[tid][2] + red[tid][3]) * (1.f / 1024.f);
        float* dst = (which == 0) ? gl : py;
        dst[((long)n * 128 + c) * 9 + tid] = s;
    }
}

// ---------------------------------------------------------------------------
__global__ __launch_bounds__(128) void attkc_kernel(
    const float* __restrict__ gl, const float* __restrict__ py,
    const float* __restrict__ w_ce, const float* __restrict__ w_gd,
    const float* __restrict__ bng, const float* __restrict__ bnb,
    const float* __restrict__ w_kc, const float* __restrict__ b_kc,
    float* __restrict__ kc)
{
    const int n = blockIdx.x, c = threadIdx.x;
    __shared__ float py_s[128][9];
    #pragma unroll
    for (int k = 0; k < 9; ++k) py_s[c][k] = py[((long)n * 128 + c) * 9 + k];
    __syncthreads();
    float g[9];
    #pragma unroll
    for (int k = 0; k < 9; ++k) g[k] = gl[((long)n * 128 + c) * 9 + k];
    float t[5];
    #pragma unroll
    for (int l = 0; l < 5; ++l) {
        float s = 0.f;
        #pragma unroll
        for (int k = 0; k < 9; ++k) s += g[k] * w_ce[l * 9 + k];
        s = s * bng[c] + bnb[c];
        t[l] = s > 0.f ? s : 0.f;
    }
    float att[9];
    #pragma unroll
    for (int k = 0; k < 9; ++k) {
        float s = 0.f;
        #pragma unroll
        for (int l = 0; l < 5; ++l) s += t[l] * w_gd[k * 5 + l];
        att[k] = 1.f / (1.f + expf(-s));
    }
    float kc0[9];
    float bk = b_kc[c];
    #pragma unroll
    for (int k = 0; k < 9; ++k) kc0[k] = bk;
    for (int c2 = 0; c2 < 128; ++c2) {
        float wv = w_kc[c * 128 + c2];
        #pragma unroll
        for (int k = 0; k < 9; ++k) kc0[k] += wv * py_s[c2][k];
    }
    #pragma unroll
    for (int k = 0; k < 9; ++k)
        kc[((long)n * 128 + c) * 9 + k] = kc0[k] * att[k];
}

// ---------------------------------------------------------------------------
// channel_after -> chan_f32 [N][128][HW] fp32
// ---------------------------------------------------------------------------
__global__ __launch_bounds__(256) void channel_kernel(
    const float* __restrict__ xd, const float* __restrict__ kc,
    float* __restrict__ chan)
{
    const int c = blockIdx.x, n = blockIdx.y;
    const int tid = threadIdx.x;
    const float* src = xd + ((long)n * 256 + c) * HW;
    __shared__ float plane[HW];
    for (int i = tid; i < HW; i += 256) plane[i] = src[i];
    float k9[9];
    #pragma unroll
    for (int k = 0; k < 9; ++k) k9[k] = kc[((long)n * 128 + c) * 9 + k];
    __syncthreads();
    for (int i = tid; i < HW; i += 256) {
        int h = i / 96, w = i % 96;
        float acc = 0.f;
        #pragma unroll
        for (int ky = 0; ky < 3; ++ky)
            #pragma unroll
            for (int kx = 0; kx < 3; ++kx) {
                int hh = h + ky - 1, ww = w + kx - 1;
                if (hh >= 0 && hh < 96 && ww >= 0 && ww < 96)
                    acc += k9[ky * 3 + kx] * plane[hh * 96 + ww];
            }
        chan[((long)n * 128 + c) * HW + i] = acc;
    }
}

// ---------------------------------------------------------------------------
// ks = 1x1 conv 128->9 on ksmid [N][128][HW] fp32
// ---------------------------------------------------------------------------
__global__ __launch_bounds__(256) void ks_kernel(
    const float* __restrict__ ksmid, const float* __restrict__ w_ks2,
    const float* __restrict__ b_ks2, float* __restrict__ ks)
{
    __shared__ float w_s[9 * 128];
    const int tid = threadIdx.x;
    for (int i = tid; i < 1152; i += 256) w_s[i] = w_ks2[i];
    __syncthreads();
    const int p = blockIdx.x * 256 + tid;
    const int n = blockIdx.y;
    float acc[9];
    #pragma unroll
    for (int k = 0; k < 9; ++k) acc[k] = b_ks2[k];
    for (int c = 0; c < 128; ++c) {
        float v = ksmid[((long)n * 128 + c) * HW + p];
        #pragma unroll
        for (int k = 0; k < 9; ++k) acc[k] += w_s[k * 128 + c] * v;
    }
    #pragma unroll
    for (int k = 0; k < 9; ++k) ks[((long)n * 9 + k) * HW + p] = acc[k];
}

// ---------------------------------------------------------------------------
__global__ __launch_bounds__(256) void ksp_kernel(
    const float* __restrict__ xd, const float* __restrict__ w_sp1,
    float* __restrict__ ksp)
{
    const int h0 = blockIdx.x * 8;
    const int n  = blockIdx.y;
    const int tid = threadIdx.x;
    __shared__ float in_s[8][10][98];
    __shared__ float w_s[1152];
    for (int i = tid; i < 1152; i += 256) w_s[i] = w_sp1[i];
    float acc[3] = {0.f, 0.f, 0.f};
    int r_[3], c_[3];
    #pragma unroll
    for (int j = 0; j < 3; ++j) { int px = tid + j * 256; r_[j] = px / 96; c_[j] = px % 96; }
    for (int ci0 = 0; ci0 < 128; ci0 += 8) {
        __syncthreads();
        for (int idx = tid; idx < 7840; idx += 256) {
            int ci = idx / 980, rem = idx % 980;
            int r = rem / 98, c = rem % 98;
            int gh = h0 + r - 1, gw = c - 1;
            float v = 0.f;
            if (gh >= 0 && gh < 96 && gw >= 0 && gw < 96)
                v = xd[((long)n * 256 + 128 + ci0 + ci) * HW + gh * 96 + gw];
            in_s[ci][r][c] = v;
        }
        __syncthreads();
        #pragma unroll 2
        for (int ci = 0; ci < 8; ++ci)
            #pragma unroll
            for (int tap = 0; tap < 9; ++tap) {
                const int ky = tap / 3, kx = tap % 3;
                float wv = w_s[(ci0 + ci) * 9 + tap];
                #pragma unroll
                for (int j = 0; j < 3; ++j)
                    acc[j] += wv * in_s[ci][r_[j] + ky][c_[j] + kx];
            }
    }
    #pragma unroll
    for (int j = 0; j < 3; ++j)
        ksp[(long)n * HW + (h0 + r_[j]) * 96 + c_[j]] = acc[j];
}

// ---------------------------------------------------------------------------
__global__ __launch_bounds__(256) void sp_kernel(
    const float* __restrict__ ksp, const float* __restrict__ w_sp,
    float* __restrict__ sp)
{
    const int p = blockIdx.x * 256 + threadIdx.x;
    const int n = blockIdx.y;
    const int h = p / 96, w = p % 96;
    const float* kp = ksp + (long)n * HW;
    float acc = 0.f;
    #pragma unroll
    for (int dy = 0; dy < 3; ++dy)
        #pragma unroll
        for (int dx = 0; dx < 3; ++dx) {
            int hh = h + dy - 1, ww = w + dx - 1;
            if (hh < 0 || hh >= 96 || ww < 0 || ww >= 96) continue;
            float s = 0.f, m = -1e30f;
            #pragma unroll
            for (int iy = 0; iy < 3; ++iy)
                #pragma unroll
                for (int ix = 0; ix < 3; ++ix) {
                    int h2 = hh + iy - 1, w2 = ww + ix - 1;
                    float v = (h2 >= 0 && h2 < 96 && w2 >= 0 && w2 < 96) ? kp[h2 * 96 + w2] : 0.f;
                    s += v; m = fmaxf(m, v);
                }
            acc += w_sp[dy * 3 + dx] * (s * (1.f / 9.f)) + w_sp[9 + dy * 3 + dx] * m;
        }
    sp[(long)n * HW + p] = 1.f / (1.f + expf(-acc));
}

// ---------------------------------------------------------------------------
// spatial_after. The reference's raw-reshape gather satisfies cc = p/72
// exactly (F = p*1152 + c*9 + kq, 82944 = 72*1152), so each output pixel p
// reads ONLY channel plane cc=p/72 of x2. One block per (cc, n): stage that
// plane in LDS, incremental decode, direct NHWC bf16 output (fb input).
// ---------------------------------------------------------------------------
__global__ __launch_bounds__(256) void spatial_kernel(
    const float* __restrict__ xd, const float* __restrict__ ks,
    const float* __restrict__ sp, __hip_bfloat16* __restrict__ catfb)
{
    const int cc = blockIdx.x;
    const int n  = blockIdx.y;
    const int tid = threadIdx.x;
    __shared__ float plane[HW];
    const float* src = xd + ((long)n * 256 + 128 + cc) * HW;
    for (int i = tid; i < HW / 4; i += 256)
        *reinterpret_cast<float4*>(&plane[i * 4]) = *reinterpret_cast<const float4*>(&src[i * 4]);
    __syncthreads();
    const int c  = tid & 127;
    const int pr = tid >> 7;
    const int c9 = c * 9;
    for (int j = 0; j < 36; ++j) {
        const int pl = pr + j * 2;
        const int p  = cc * 72 + pl;
        float spv = sp[(long)n * HW + p];
        float kv[9];
        #pragma unroll
        for (int k = 0; k < 9; ++k) kv[k] = ks[((long)n * 9 + k) * HW + p] * spv;
        const int base = pl * 1152 + c9;
        int kk0 = base / 9216;
        int r20 = base - kk0 * 9216;
        int h20 = r20 / 96;
        int w20 = r20 - h20 * 96;
        float acc = 0.f;
        #pragma unroll
        for (int k = 0; k < 9; ++k) {
            int kk = kk0, h2 = h20, w2 = w20 + k;
            if (w2 >= 96) { h2 += 1; w2 -= 96; }
            if (h2 >= 96) { kk += 1; h2 -= 96; }
            int hh = h2 + kk / 3 - 1;
            int ww = w2 + kk % 3 - 1;
            float v = (hh >= 0 && hh < 96 && ww >= 0 && ww < 96) ? plane[hh * 96 + ww] : 0.f;
            acc += v * kv[k];
        }
        catfb[((long)n * HW + p) * 256 + 128 + c] = __float2bfloat16(acc);
    }
}

// ---------------------------------------------------------------------------
extern "C" void kernel_launch(void* const* d_in, const int* in_sizes, int n_in,
                              void* d_out, int out_size, void* d_ws, size_t ws_size,
                              hipStream_t stream)
{
    const float* x      = (const float*)d_in[0];
    const float* y      = (const float*)d_in[1];
    const float* w_down = (const float*)d_in[2];
    const float* b_down = (const float*)d_in[3];
    const float* w_ce   = (const float*)d_in[4];
    const float* w_gd   = (const float*)d_in[5];
    const float* bn_g   = (const float*)d_in[6];
    const float* bn_b   = (const float*)d_in[7];
    const float* w_kc   = (const float*)d_in[8];
    const float* b_kc   = (const float*)d_in[9];
    const float* w_ks1  = (const float*)d_in[10];
    const float* b_ks1  = (const float*)d_in[11];
    const float* w_ks2  = (const float*)d_in[12];
    const float* b_ks2  = (const float*)d_in[13];
    const float* w_sp1  = (const float*)d_in[14];
    const float* w_sp   = (const float*)d_in[15];
    const float* w_fb   = (const float*)d_in[16];
    const float* b_fb   = (const float*)d_in[17];
    const float* w_fuse = (const float*)d_in[18];
    const float* bn2_g  = (const float*)d_in[19];
    const float* bn2_b  = (const float*)d_in[20];
    const float* prelu  = (const float*)d_in[21];
    float* out = (float*)d_out;
    char* ws = (char*)d_ws;

    const long HWl = HW;
    // --- workspace layout ---
    float* xd = (float*)ws;                               ws += 8L * 256 * HWl * 4;  // 75.5MB
    char*  cfbase = ws;                                   ws += 8L * HWl * 512 * 2;  // 75.5MB
    __hip_bfloat16* cat_fuse = (__hip_bfloat16*)cfbase;   // [N][HW][512] bf16 (final fuse input)
    __hip_bfloat16* x_t      = (__hip_bfloat16*)cfbase;   // [N][HW][512] bf16 (dead after conv1x1)
    float* chan_f32 = (float*)cfbase;                     // [N][128][HW] fp32 (lower half)
    float* ksmid    = (float*)(cfbase + 8L * HWl * 512);  // [N][128][HW] fp32 (upper half)
    __hip_bfloat16* catfb_bf = (__hip_bfloat16*)ws;       ws += 8L * HWl * 256 * 2;  // 37.7MB
    __hip_bfloat16* y2t      = (__hip_bfloat16*)ws;       ws += 8L * HWl * 128 * 2;  // 18.9MB
    __hip_bfloat16* wdown_bf = (__hip_bfloat16*)ws;       ws += 1L * 256 * 512 * 2;
    __hip_bfloat16* wks1_bf  = (__hip_bfloat16*)ws;       ws += 9L * 128 * 128 * 2;
    __hip_bfloat16* wfb_bf   = (__hip_bfloat16*)ws;       ws += 9L * 256 * 256 * 2;
    __hip_bfloat16* wfuse_bf = (__hip_bfloat16*)ws;       ws += 9L * 256 * 512 * 2;
    float* ks   = (float*)ws;  ws += 8L * 9 * HWl * 4;
    float* ksp  = (float*)ws;  ws += 8L * HWl * 4;
    float* spb  = (float*)ws;  ws += 8L * HWl * 4;
    float* gl   = (float*)ws;  ws += 8L * 128 * 9 * 4;
    float* py   = (float*)ws;  ws += 8L * 128 * 9 * 4;
    float* kc   = (float*)ws;  ws += 8L * 128 * 9 * 4;
    __hip_bfloat16* zp = (__hip_bfloat16*)ws;  ws += 256;

    hipMemsetAsync((void*)zp, 0, 256, stream);

    // weight conversions
    wconv_kernel<<<dim3(512), 256, 0, stream>>>(w_down, wdown_bf, 256, 512, 1);
    wconv_kernel<<<dim3(64),  256, 0, stream>>>(w_ks1,  wks1_bf,  128, 128, 9);
    wconv_kernel<<<dim3(256), 256, 0, stream>>>(w_fb,   wfb_bf,   256, 256, 9);
    wconv_kernel<<<dim3(512), 256, 0, stream>>>(w_fuse, wfuse_bf, 256, 512, 9);

    // x -> NHWC bf16 (x_t @ cat_fuse region), then 1x1 down-conv via MFMA
    nchw2nhwc_kernel<<<dim3(144, 16, 8), 256, 0, stream>>>(x, 512L * HWl, x_t, 512);
    mfma_conv<512, 1><<<dim3(24, 4, 8), 256, 57344, stream>>>(
        x_t, wdown_bf, b_down, xd, 256L * HWl, nullptr, 0, 256,
        nullptr, nullptr, nullptr, zp);

    // y2 -> NHWC bf16
    nchw2nhwc_kernel<<<dim3(144, 4, 8), 256, 0, stream>>>(y + 128L * HWl, 256L * HWl, y2t, 128);

    // pools / attention / channel_after (x_t dead now; chan_f32 @ cat_fuse lo)
    pool_kernel<<<dim3(128, 8, 2), 256, 0, stream>>>(xd, y, gl, py);
    attkc_kernel<<<dim3(8), 128, 0, stream>>>(gl, py, w_ce, w_gd, bn_g, bn_b, w_kc, b_kc, kc);
    channel_kernel<<<dim3(128, 8), 256, 0, stream>>>(xd, kc, chan_f32);

    // ks_mid = conv3x3(y2) via MFMA -> ksmid fp32 (@ cat_fuse hi)
    mfma_conv<128, 9><<<dim3(24, 2, 8), 256, 148992, stream>>>(
        y2t, wks1_bf, b_ks1, ksmid, 128L * HWl, nullptr, 0, 128,
        nullptr, nullptr, nullptr, zp);
    ks_kernel<<<dim3(36, 8), 256, 0, stream>>>(ksmid, w_ks2, b_ks2, ks);

    // ksp / sp
    ksp_kernel<<<dim3(12, 8), 256, 0, stream>>>(xd, w_sp1, ksp);
    sp_kernel<<<dim3(36, 8), 256, 0, stream>>>(ksp, w_sp, spb);

    // spatial_after -> catfb ch128..255 (direct NHWC bf16)
    spatial_kernel<<<dim3(128, 8), 256, 0, stream>>>(xd, ks, spb, catfb_bf);
    // channel_after -> catfb ch0..127
    nchw2nhwc_kernel<<<dim3(144, 4, 8), 256, 0, stream>>>(chan_f32, 128L * HWl, catfb_bf, 256);

    // xd -> cat_fuse ch0..255 (chan_f32/ksmid dead now)
    nchw2nhwc_kernel<<<dim3(144, 8, 8), 256, 0, stream>>>(xd, 256L * HWl, cat_fuse, 512);

    // r1 = conv3x3(catfb, w_fb)+b -> cat_fuse ch256..511 (NHWC bf16)
    mfma_conv<256, 9><<<dim3(24, 4, 8), 256, 148992, stream>>>(
        catfb_bf, wfb_bf, b_fb, nullptr, 0, cat_fuse + 256, 512, 256,
        nullptr, nullptr, nullptr, zp);

    // out = prelu(bn(conv3x3(cat_fuse, w_fuse)))
    mfma_conv<512, 9><<<dim3(24, 4, 8), 256, 148992, stream>>>(
        cat_fuse, wfuse_bf, nullptr, out, 256L * HWl, nullptr, 0, 256,
        bn2_g, bn2_b, prelu, zp);
}